// Round 1
// baseline (1190.886 us; speedup 1.0000x reference)
//
#include <hip/hip_runtime.h>

#define S_LEN 2048
#define DMODEL 1024
#define NH 16
#define DK 64
#define BATCH 2
#define BS (BATCH * S_LEN)  // 4096

typedef _Float16 f16;
typedef _Float16 f16x8 __attribute__((ext_vector_type(8)));
typedef _Float16 f16x4 __attribute__((ext_vector_type(4)));
typedef float f32x4 __attribute__((ext_vector_type(4)));

__device__ __forceinline__ f32x4 mfma16(f16x8 a, f16x8 b, f32x4 c) {
  return __builtin_amdgcn_mfma_f32_16x16x32_f16(a, b, c, 0, 0, 0);
}

// C[M=4096][N=1024] = A[4096][1024] * W[1024][1024]^T + bias   (NT GEMM)
// MODE 0: write f16 head-split [B][H][S][DK]
// MODE 1: write f16 head-split transposed [B][H][DK][S]
// MODE 2: write fp32 row-major [M][N]
template <typename AT, int MODE>
__global__ __launch_bounds__(256, 2) void gemm_nt(const AT* __restrict__ A,
                                                  const float* __restrict__ W,
                                                  const float* __restrict__ bias,
                                                  void* __restrict__ outp) {
  __shared__ f16 As[128][40];
  __shared__ f16 Ws[128][40];
  const int t = threadIdx.x;
  const int m0 = blockIdx.y * 128;
  const int n0 = blockIdx.x * 128;
  const int wave = t >> 6, lane = t & 63;
  const int wr = wave >> 1, wc = wave & 1;
  const int lcol = lane & 15, kq = lane >> 4;

  f32x4 acc[4][4];
  const f32x4 zero = {0.f, 0.f, 0.f, 0.f};
#pragma unroll
  for (int i = 0; i < 4; ++i)
#pragma unroll
    for (int j = 0; j < 4; ++j) acc[i][j] = zero;

  for (int k0 = 0; k0 < DMODEL; k0 += 32) {
    // stage A tile 128x32
    if constexpr (sizeof(AT) == 4) {
#pragma unroll
      for (int i = 0; i < 4; ++i) {
        int f = t + i * 256;
        int r = f >> 3, c = (f & 7) << 2;
        const float4 v = *reinterpret_cast<const float4*>(
            &((const float*)A)[(size_t)(m0 + r) * DMODEL + k0 + c]);
        f16x4 h = {(f16)v.x, (f16)v.y, (f16)v.z, (f16)v.w};
        *reinterpret_cast<f16x4*>(&As[r][c]) = h;
      }
    } else {
#pragma unroll
      for (int i = 0; i < 2; ++i) {
        int f = t + i * 256;
        int r = f >> 2, c = (f & 3) << 3;
        *reinterpret_cast<f16x8*>(&As[r][c]) = *reinterpret_cast<const f16x8*>(
            &((const f16*)A)[(size_t)(m0 + r) * DMODEL + k0 + c]);
      }
    }
    // stage W tile 128x32 (fp32 -> f16)
#pragma unroll
    for (int i = 0; i < 4; ++i) {
      int f = t + i * 256;
      int r = f >> 3, c = (f & 7) << 2;
      const float4 v = *reinterpret_cast<const float4*>(
          &W[(size_t)(n0 + r) * DMODEL + k0 + c]);
      f16x4 h = {(f16)v.x, (f16)v.y, (f16)v.z, (f16)v.w};
      *reinterpret_cast<f16x4*>(&Ws[r][c]) = h;
    }
    __syncthreads();
    f16x8 af[4], bf[4];
#pragma unroll
    for (int fr = 0; fr < 4; ++fr)
      af[fr] = *reinterpret_cast<const f16x8*>(&As[wr * 64 + fr * 16 + lcol][kq * 8]);
#pragma unroll
    for (int fc = 0; fc < 4; ++fc)
      bf[fc] = *reinterpret_cast<const f16x8*>(&Ws[wc * 64 + fc * 16 + lcol][kq * 8]);
#pragma unroll
    for (int fr = 0; fr < 4; ++fr)
#pragma unroll
      for (int fc = 0; fc < 4; ++fc) acc[fr][fc] = mfma16(af[fr], bf[fc], acc[fr][fc]);
    __syncthreads();
  }

#pragma unroll
  for (int fc = 0; fc < 4; ++fc) {
    const int gj = n0 + wc * 64 + fc * 16 + lcol;
    const float bv = bias[gj];
#pragma unroll
    for (int fr = 0; fr < 4; ++fr) {
#pragma unroll
      for (int r = 0; r < 4; ++r) {
        const int gi = m0 + wr * 64 + fr * 16 + kq * 4 + r;
        const float val = acc[fr][fc][r] + bv;
        if constexpr (MODE == 0) {
          const int b = gi >> 11, s = gi & 2047, h = gj >> 6, dk = gj & 63;
          ((f16*)outp)[(((size_t)(b * NH + h) * S_LEN) + s) * DK + dk] = (f16)val;
        } else if constexpr (MODE == 1) {
          const int b = gi >> 11, s = gi & 2047, h = gj >> 6, dk = gj & 63;
          ((f16*)outp)[(((size_t)(b * NH + h) * DK) + dk) * S_LEN + s] = (f16)val;
        } else {
          ((float*)outp)[(size_t)gi * DMODEL + gj] = val;
        }
      }
    }
  }
}

// scores: per (b,h): Sc[2048][2048] = qh[2048][64] * kh[2048][64]^T * 0.125, masked
__global__ __launch_bounds__(256, 2) void scores_kernel(const f16* __restrict__ qh,
                                                        const f16* __restrict__ kh,
                                                        const int* __restrict__ mask,
                                                        float* __restrict__ attn) {
  __shared__ f16 Qs[128][72];
  __shared__ f16 Ks[128][72];
  const int t = threadIdx.x;
  const int bh = blockIdx.z, b = bh >> 4;
  const int i0 = blockIdx.y * 128, j0 = blockIdx.x * 128;
  const f16* Q = qh + (size_t)bh * S_LEN * DK;
  const f16* K = kh + (size_t)bh * S_LEN * DK;
  float* Sc = attn + (size_t)bh * S_LEN * S_LEN;

#pragma unroll
  for (int i = 0; i < 4; ++i) {
    int f = t + i * 256;
    int r = f >> 3, c = (f & 7) << 3;
    *reinterpret_cast<f16x8*>(&Qs[r][c]) =
        *reinterpret_cast<const f16x8*>(&Q[(size_t)(i0 + r) * DK + c]);
    *reinterpret_cast<f16x8*>(&Ks[r][c]) =
        *reinterpret_cast<const f16x8*>(&K[(size_t)(j0 + r) * DK + c]);
  }
  __syncthreads();

  const int wave = t >> 6, lane = t & 63;
  const int wr = wave >> 1, wc = wave & 1;
  const int lcol = lane & 15, kq = lane >> 4;
  f32x4 acc[4][4];
  const f32x4 zero = {0.f, 0.f, 0.f, 0.f};
#pragma unroll
  for (int i = 0; i < 4; ++i)
#pragma unroll
    for (int j = 0; j < 4; ++j) acc[i][j] = zero;

#pragma unroll
  for (int kk = 0; kk < 64; kk += 32) {
    f16x8 af[4], bf[4];
#pragma unroll
    for (int fr = 0; fr < 4; ++fr)
      af[fr] = *reinterpret_cast<const f16x8*>(&Qs[wr * 64 + fr * 16 + lcol][kq * 8 + kk]);
#pragma unroll
    for (int fc = 0; fc < 4; ++fc)
      bf[fc] = *reinterpret_cast<const f16x8*>(&Ks[wc * 64 + fc * 16 + lcol][kq * 8 + kk]);
#pragma unroll
    for (int fr = 0; fr < 4; ++fr)
#pragma unroll
      for (int fc = 0; fc < 4; ++fc) acc[fr][fc] = mfma16(af[fr], bf[fc], acc[fr][fc]);
  }

  const float NEG_INF = -__builtin_inff();
#pragma unroll
  for (int fc = 0; fc < 4; ++fc) {
    const int gj = j0 + wc * 64 + fc * 16 + lcol;
    const int mv = mask[b * S_LEN + gj];
#pragma unroll
    for (int fr = 0; fr < 4; ++fr) {
#pragma unroll
      for (int r = 0; r < 4; ++r) {
        const int gi = i0 + wr * 64 + fr * 16 + kq * 4 + r;
        const float val = mv ? acc[fr][fc][r] * 0.125f : NEG_INF;
        Sc[((size_t)gi << 11) + gj] = val;
      }
    }
  }
}

// in-place row softmax; one block per row of 2048 fp32
__global__ __launch_bounds__(256, 4) void softmax_kernel(float* __restrict__ attn) {
  const size_t row = blockIdx.x;
  float* p = attn + (row << 11);
  const int t = threadIdx.x;
  const int wv = t >> 6, ln = t & 63;
  float4 a = *reinterpret_cast<float4*>(p + t * 8);
  float4 b = *reinterpret_cast<float4*>(p + t * 8 + 4);
  float x[8] = {a.x, a.y, a.z, a.w, b.x, b.y, b.z, b.w};
  float m = x[0];
#pragma unroll
  for (int j = 1; j < 8; ++j) m = fmaxf(m, x[j]);
#pragma unroll
  for (int o = 32; o > 0; o >>= 1) m = fmaxf(m, __shfl_down(m, o));
  __shared__ float redm[4], reds[4];
  if (ln == 0) redm[wv] = m;
  __syncthreads();
  m = fmaxf(fmaxf(redm[0], redm[1]), fmaxf(redm[2], redm[3]));
  float e[8], s = 0.f;
#pragma unroll
  for (int j = 0; j < 8; ++j) {
    e[j] = __expf(x[j] - m);
    s += e[j];
  }
#pragma unroll
  for (int o = 32; o > 0; o >>= 1) s += __shfl_down(s, o);
  if (ln == 0) reds[wv] = s;
  __syncthreads();
  s = reds[0] + reds[1] + reds[2] + reds[3];
  const float inv = 1.0f / s;
  float4 oa = {e[0] * inv, e[1] * inv, e[2] * inv, e[3] * inv};
  float4 ob = {e[4] * inv, e[5] * inv, e[6] * inv, e[7] * inv};
  *reinterpret_cast<float4*>(p + t * 8) = oa;
  *reinterpret_cast<float4*>(p + t * 8 + 4) = ob;
}

// per (b,h): ctx rows = attn[2048][2048](fp32) * vh[2048][64] via vhT[64][2048]
__global__ __launch_bounds__(256, 2) void pv_kernel(const float* __restrict__ attn,
                                                    const f16* __restrict__ vhT,
                                                    f16* __restrict__ ctx) {
  __shared__ f16 As[128][72];
  __shared__ f16 Vs[64][72];
  const int t = threadIdx.x;
  const int bh = blockIdx.y, b = bh >> 4, h = bh & 15;
  const int i0 = blockIdx.x * 128;
  const float* A = attn + (size_t)bh * S_LEN * S_LEN;
  const f16* V = vhT + (size_t)bh * DK * S_LEN;
  const int wave = t >> 6, lane = t & 63;
  const int lcol = lane & 15, kq = lane >> 4;

  f32x4 acc[2][4];
  const f32x4 zero = {0.f, 0.f, 0.f, 0.f};
#pragma unroll
  for (int i = 0; i < 2; ++i)
#pragma unroll
    for (int j = 0; j < 4; ++j) acc[i][j] = zero;

  for (int s0 = 0; s0 < S_LEN; s0 += 64) {
#pragma unroll
    for (int i = 0; i < 8; ++i) {
      int f = t + i * 256;
      int r = f >> 4, c = (f & 15) << 2;
      const float4 v =
          *reinterpret_cast<const float4*>(&A[((size_t)(i0 + r) << 11) + s0 + c]);
      f16x4 hv = {(f16)v.x, (f16)v.y, (f16)v.z, (f16)v.w};
      *reinterpret_cast<f16x4*>(&As[r][c]) = hv;
    }
#pragma unroll
    for (int i = 0; i < 2; ++i) {
      int f = t + i * 256;
      int r = f >> 3, c = (f & 7) << 3;
      *reinterpret_cast<f16x8*>(&Vs[r][c]) =
          *reinterpret_cast<const f16x8*>(&V[(size_t)r * S_LEN + s0 + c]);
    }
    __syncthreads();
#pragma unroll
    for (int kk = 0; kk < 64; kk += 32) {
      f16x8 af[2], bf[4];
#pragma unroll
      for (int fr = 0; fr < 2; ++fr)
        af[fr] =
            *reinterpret_cast<const f16x8*>(&As[wave * 32 + fr * 16 + lcol][kq * 8 + kk]);
#pragma unroll
      for (int fc = 0; fc < 4; ++fc)
        bf[fc] = *reinterpret_cast<const f16x8*>(&Vs[fc * 16 + lcol][kq * 8 + kk]);
#pragma unroll
      for (int fr = 0; fr < 2; ++fr)
#pragma unroll
        for (int fc = 0; fc < 4; ++fc) acc[fr][fc] = mfma16(af[fr], bf[fc], acc[fr][fc]);
    }
    __syncthreads();
  }

#pragma unroll
  for (int fc = 0; fc < 4; ++fc) {
    const int dk = fc * 16 + lcol;
#pragma unroll
    for (int fr = 0; fr < 2; ++fr) {
#pragma unroll
      for (int r = 0; r < 4; ++r) {
        const int s = i0 + wave * 32 + fr * 16 + kq * 4 + r;
        ctx[(size_t)(b * S_LEN + s) * DMODEL + h * DK + dk] = (f16)acc[fr][fc][r];
      }
    }
  }
}

extern "C" void kernel_launch(void* const* d_in, const int* in_sizes, int n_in,
                              void* d_out, int out_size, void* d_ws, size_t ws_size,
                              hipStream_t stream) {
  const float* q = (const float*)d_in[0];
  const float* k = (const float*)d_in[1];
  const float* v = (const float*)d_in[2];
  const int* mask = (const int*)d_in[3];
  const float* w_q = (const float*)d_in[4];
  const float* b_q = (const float*)d_in[5];
  const float* w_v = (const float*)d_in[6];
  const float* b_v = (const float*)d_in[7];
  const float* w_o = (const float*)d_in[8];
  const float* b_o = (const float*)d_in[9];

  float* out = (float*)d_out;
  float* attn = out + (size_t)BS * DMODEL;  // output 1 region

  f16* qh = (f16*)d_ws;                       // [B][H][S][DK]
  f16* kh = qh + (size_t)BS * DMODEL;         // [B][H][S][DK]
  f16* vhT = kh + (size_t)BS * DMODEL;        // [B][H][DK][S]
  f16* ctx = vhT + (size_t)BS * DMODEL;       // [BS][DMODEL]

  dim3 gblk(8, 32);
  gemm_nt<float, 0><<<gblk, 256, 0, stream>>>(q, w_q, b_q, qh);
  gemm_nt<float, 0><<<gblk, 256, 0, stream>>>(k, w_q, b_q, kh);
  gemm_nt<float, 1><<<gblk, 256, 0, stream>>>(v, w_v, b_v, vhT);
  scores_kernel<<<dim3(16, 16, 32), 256, 0, stream>>>(qh, kh, mask, attn);
  softmax_kernel<<<dim3(65536), 256, 0, stream>>>(attn);
  pv_kernel<<<dim3(16, 32), 256, 0, stream>>>(attn, vhT, ctx);
  gemm_nt<_Float16, 2><<<gblk, 256, 0, stream>>>(ctx, w_o, b_o, d_out);
}

// Round 2
// 1005.931 us; speedup vs baseline: 1.1839x; 1.1839x over previous
//
#include <hip/hip_runtime.h>

#define S_LEN 2048
#define DMODEL 1024
#define NH 16
#define DK 64
#define BATCH 2
#define BS (BATCH * S_LEN)  // 4096

typedef _Float16 f16;
typedef _Float16 f16x8 __attribute__((ext_vector_type(8)));
typedef _Float16 f16x4 __attribute__((ext_vector_type(4)));
typedef float f32x4 __attribute__((ext_vector_type(4)));

__device__ __forceinline__ f32x4 mfma16(f16x8 a, f16x8 b, f32x4 c) {
  return __builtin_amdgcn_mfma_f32_16x16x32_f16(a, b, c, 0, 0, 0);
}

// C[M=4096][N=1024] = A[4096][1024] * W[1024][1024]^T + bias   (NT GEMM)
// MODE 0: write f16 head-split [B][H][S][DK]
// MODE 1: write f16 head-split transposed [B][H][DK][S]
// MODE 2: write fp32 row-major [M][N]
template <typename AT, int MODE>
__global__ __launch_bounds__(256, 2) void gemm_nt(const AT* __restrict__ A,
                                                  const float* __restrict__ W,
                                                  const float* __restrict__ bias,
                                                  void* __restrict__ outp) {
  __shared__ f16 As[128][40];
  __shared__ f16 Ws[128][40];
  const int t = threadIdx.x;
  const int m0 = blockIdx.y * 128;
  const int n0 = blockIdx.x * 128;
  const int wave = t >> 6, lane = t & 63;
  const int wr = wave >> 1, wc = wave & 1;
  const int lcol = lane & 15, kq = lane >> 4;

  f32x4 acc[4][4];
  const f32x4 zero = {0.f, 0.f, 0.f, 0.f};
#pragma unroll
  for (int i = 0; i < 4; ++i)
#pragma unroll
    for (int j = 0; j < 4; ++j) acc[i][j] = zero;

  for (int k0 = 0; k0 < DMODEL; k0 += 32) {
    if constexpr (sizeof(AT) == 4) {
#pragma unroll
      for (int i = 0; i < 4; ++i) {
        int f = t + i * 256;
        int r = f >> 3, c = (f & 7) << 2;
        const float4 v = *reinterpret_cast<const float4*>(
            &((const float*)A)[(size_t)(m0 + r) * DMODEL + k0 + c]);
        f16x4 h = {(f16)v.x, (f16)v.y, (f16)v.z, (f16)v.w};
        *reinterpret_cast<f16x4*>(&As[r][c]) = h;
      }
    } else {
#pragma unroll
      for (int i = 0; i < 2; ++i) {
        int f = t + i * 256;
        int r = f >> 2, c = (f & 3) << 3;
        *reinterpret_cast<f16x8*>(&As[r][c]) = *reinterpret_cast<const f16x8*>(
            &((const f16*)A)[(size_t)(m0 + r) * DMODEL + k0 + c]);
      }
    }
#pragma unroll
    for (int i = 0; i < 4; ++i) {
      int f = t + i * 256;
      int r = f >> 3, c = (f & 7) << 2;
      const float4 v = *reinterpret_cast<const float4*>(
          &W[(size_t)(n0 + r) * DMODEL + k0 + c]);
      f16x4 h = {(f16)v.x, (f16)v.y, (f16)v.z, (f16)v.w};
      *reinterpret_cast<f16x4*>(&Ws[r][c]) = h;
    }
    __syncthreads();
    f16x8 af[4], bf[4];
#pragma unroll
    for (int fr = 0; fr < 4; ++fr)
      af[fr] = *reinterpret_cast<const f16x8*>(&As[wr * 64 + fr * 16 + lcol][kq * 8]);
#pragma unroll
    for (int fc = 0; fc < 4; ++fc)
      bf[fc] = *reinterpret_cast<const f16x8*>(&Ws[wc * 64 + fc * 16 + lcol][kq * 8]);
#pragma unroll
    for (int fr = 0; fr < 4; ++fr)
#pragma unroll
      for (int fc = 0; fc < 4; ++fc) acc[fr][fc] = mfma16(af[fr], bf[fc], acc[fr][fc]);
    __syncthreads();
  }

#pragma unroll
  for (int fc = 0; fc < 4; ++fc) {
    const int gj = n0 + wc * 64 + fc * 16 + lcol;
    const float bv = bias[gj];
#pragma unroll
    for (int fr = 0; fr < 4; ++fr) {
#pragma unroll
      for (int r = 0; r < 4; ++r) {
        const int gi = m0 + wr * 64 + fr * 16 + kq * 4 + r;
        const float val = acc[fr][fc][r] + bv;
        if constexpr (MODE == 0) {
          const int b = gi >> 11, s = gi & 2047, h = gj >> 6, dk = gj & 63;
          ((f16*)outp)[(((size_t)(b * NH + h) * S_LEN) + s) * DK + dk] = (f16)val;
        } else if constexpr (MODE == 1) {
          const int b = gi >> 11, s = gi & 2047, h = gj >> 6, dk = gj & 63;
          ((f16*)outp)[(((size_t)(b * NH + h) * DK) + dk) * S_LEN + s] = (f16)val;
        } else {
          ((float*)outp)[(size_t)gi * DMODEL + gj] = val;
        }
      }
    }
  }
}

// Pass 1: per (bh, 128-row tile): sweep K, compute row max m and row sum l of
// exp(s - m) with masked cols excluded. MFMA order identical to pass 2.
__global__ __launch_bounds__(256, 2) void stats_kernel(
    const f16* __restrict__ qh, const f16* __restrict__ kh,
    const int* __restrict__ mask, float* __restrict__ m_out,
    float* __restrict__ l_out) {
  __shared__ f16 Ks[64][72];
  __shared__ int msk[S_LEN];
  const int t = threadIdx.x;
  const int bh = blockIdx.y, b = bh >> 4;
  const int i0 = blockIdx.x * 128;
  const int wave = t >> 6, lane = t & 63;
  const int lcol = lane & 15, kq = lane >> 4;
  const int rbase = i0 + wave * 32;
  const f16* Q = qh + (size_t)bh * S_LEN * DK;
  const f16* K = kh + (size_t)bh * S_LEN * DK;

  for (int i = t; i < S_LEN; i += 256) msk[i] = mask[b * S_LEN + i];

  f16x8 aq[2][2];
#pragma unroll
  for (int rt = 0; rt < 2; ++rt)
#pragma unroll
    for (int ks = 0; ks < 2; ++ks)
      aq[rt][ks] = *reinterpret_cast<const f16x8*>(
          &Q[(size_t)(rbase + rt * 16 + lcol) * DK + ks * 32 + kq * 8]);

  const float NEG = -__builtin_inff();
  float m_run[2][4], l_run[2][4];
#pragma unroll
  for (int rt = 0; rt < 2; ++rt)
#pragma unroll
    for (int r = 0; r < 4; ++r) {
      m_run[rt][r] = NEG;
      l_run[rt][r] = 0.f;
    }

  for (int j0 = 0; j0 < S_LEN; j0 += 64) {
    __syncthreads();
#pragma unroll
    for (int i = 0; i < 2; ++i) {
      int f = t + i * 256;
      int r = f >> 3, c = (f & 7) << 3;
      *reinterpret_cast<f16x8*>(&Ks[r][c]) =
          *reinterpret_cast<const f16x8*>(&K[(size_t)(j0 + r) * DK + c]);
    }
    __syncthreads();
    float sv[2][4][4];
#pragma unroll
    for (int jt = 0; jt < 4; ++jt) {
      const f16x8 bk0 = *reinterpret_cast<const f16x8*>(&Ks[jt * 16 + lcol][kq * 8]);
      const f16x8 bk1 =
          *reinterpret_cast<const f16x8*>(&Ks[jt * 16 + lcol][kq * 8 + 32]);
      const int mv = msk[j0 + jt * 16 + lcol];
#pragma unroll
      for (int rt = 0; rt < 2; ++rt) {
        f32x4 c = {0.f, 0.f, 0.f, 0.f};
        c = mfma16(aq[rt][0], bk0, c);
        c = mfma16(aq[rt][1], bk1, c);
#pragma unroll
        for (int r = 0; r < 4; ++r) sv[rt][jt][r] = mv ? c[r] * 0.125f : NEG;
      }
    }
#pragma unroll
    for (int rt = 0; rt < 2; ++rt) {
#pragma unroll
      for (int r = 0; r < 4; ++r) {
        float mx = fmaxf(fmaxf(sv[rt][0][r], sv[rt][1][r]),
                         fmaxf(sv[rt][2][r], sv[rt][3][r]));
#pragma unroll
        for (int o = 1; o < 16; o <<= 1) mx = fmaxf(mx, __shfl_xor(mx, o));
        const float mnew = fmaxf(m_run[rt][r], mx);
        float es = 0.f;
#pragma unroll
        for (int jt = 0; jt < 4; ++jt) es += __expf(sv[rt][jt][r] - mnew);
#pragma unroll
        for (int o = 1; o < 16; o <<= 1) es += __shfl_xor(es, o);
        const float fac = (m_run[rt][r] > NEG) ? __expf(m_run[rt][r] - mnew) : 0.f;
        l_run[rt][r] = l_run[rt][r] * fac + es;
        m_run[rt][r] = mnew;
      }
    }
  }
  if (lcol == 0) {
#pragma unroll
    for (int rt = 0; rt < 2; ++rt)
#pragma unroll
      for (int r = 0; r < 4; ++r) {
        const int row = (bh << 11) + rbase + rt * 16 + kq * 4 + r;
        m_out[row] = m_run[rt][r];
        l_out[row] = l_run[rt][r];
      }
  }
}

// Pass 2: recompute S tiles (bit-identical), write attn = exp(s-m)/l once,
// and accumulate O = P·V via LDS round-trip of P (C-layout -> A-layout).
__global__ __launch_bounds__(256, 2) void attn_pv_kernel(
    const f16* __restrict__ qh, const f16* __restrict__ kh,
    const f16* __restrict__ vhT, const int* __restrict__ mask,
    const float* __restrict__ m_in, const float* __restrict__ l_in,
    float* __restrict__ attn, f16* __restrict__ ctx) {
  __shared__ f16 Ks[64][72];
  __shared__ f16 Vs[64][72];
  __shared__ f16 Ps[4][32][72];
  __shared__ int msk[S_LEN];
  const int t = threadIdx.x;
  const int bh = blockIdx.y, b = bh >> 4, h = bh & 15;
  const int i0 = blockIdx.x * 128;
  const int wave = t >> 6, lane = t & 63;
  const int lcol = lane & 15, kq = lane >> 4;
  const int rbase = i0 + wave * 32;
  const f16* Q = qh + (size_t)bh * S_LEN * DK;
  const f16* K = kh + (size_t)bh * S_LEN * DK;
  const f16* V = vhT + (size_t)bh * DK * S_LEN;
  float* Sc = attn + (size_t)bh * S_LEN * S_LEN;

  for (int i = t; i < S_LEN; i += 256) msk[i] = mask[b * S_LEN + i];

  f16x8 aq[2][2];
#pragma unroll
  for (int rt = 0; rt < 2; ++rt)
#pragma unroll
    for (int ks = 0; ks < 2; ++ks)
      aq[rt][ks] = *reinterpret_cast<const f16x8*>(
          &Q[(size_t)(rbase + rt * 16 + lcol) * DK + ks * 32 + kq * 8]);

  float m_ld[2][4], il[2][4];
#pragma unroll
  for (int rt = 0; rt < 2; ++rt)
#pragma unroll
    for (int r = 0; r < 4; ++r) {
      const int row = (bh << 11) + rbase + rt * 16 + kq * 4 + r;
      m_ld[rt][r] = m_in[row];
      il[rt][r] = 1.0f / l_in[row];
    }

  f32x4 o[2][4];
  const f32x4 zero = {0.f, 0.f, 0.f, 0.f};
#pragma unroll
  for (int rt = 0; rt < 2; ++rt)
#pragma unroll
    for (int d = 0; d < 4; ++d) o[rt][d] = zero;

  for (int j0 = 0; j0 < S_LEN; j0 += 64) {
    __syncthreads();
#pragma unroll
    for (int i = 0; i < 2; ++i) {
      int f = t + i * 256;
      int r = f >> 3, c = (f & 7) << 3;
      *reinterpret_cast<f16x8*>(&Ks[r][c]) =
          *reinterpret_cast<const f16x8*>(&K[(size_t)(j0 + r) * DK + c]);
      *reinterpret_cast<f16x8*>(&Vs[r][c]) =
          *reinterpret_cast<const f16x8*>(&V[(size_t)r * S_LEN + j0 + c]);
    }
    __syncthreads();
#pragma unroll
    for (int jt = 0; jt < 4; ++jt) {
      const f16x8 bk0 = *reinterpret_cast<const f16x8*>(&Ks[jt * 16 + lcol][kq * 8]);
      const f16x8 bk1 =
          *reinterpret_cast<const f16x8*>(&Ks[jt * 16 + lcol][kq * 8 + 32]);
      const int mv = msk[j0 + jt * 16 + lcol];
#pragma unroll
      for (int rt = 0; rt < 2; ++rt) {
        f32x4 c = {0.f, 0.f, 0.f, 0.f};
        c = mfma16(aq[rt][0], bk0, c);
        c = mfma16(aq[rt][1], bk1, c);
#pragma unroll
        for (int r = 0; r < 4; ++r) {
          const float p =
              mv ? __expf(c[r] * 0.125f - m_ld[rt][r]) * il[rt][r] : 0.f;
          Sc[((size_t)(rbase + rt * 16 + kq * 4 + r) << 11) + j0 + jt * 16 + lcol] =
              p;
          Ps[wave][rt * 16 + kq * 4 + r][jt * 16 + lcol] = (f16)p;
        }
      }
    }
#pragma unroll
    for (int ks = 0; ks < 2; ++ks) {
      f16x8 ap[2], bv[4];
#pragma unroll
      for (int rt = 0; rt < 2; ++rt)
        ap[rt] =
            *reinterpret_cast<const f16x8*>(&Ps[wave][rt * 16 + lcol][ks * 32 + kq * 8]);
#pragma unroll
      for (int d = 0; d < 4; ++d)
        bv[d] = *reinterpret_cast<const f16x8*>(&Vs[d * 16 + lcol][ks * 32 + kq * 8]);
#pragma unroll
      for (int rt = 0; rt < 2; ++rt)
#pragma unroll
        for (int d = 0; d < 4; ++d) o[rt][d] = mfma16(ap[rt], bv[d], o[rt][d]);
    }
  }

#pragma unroll
  for (int d = 0; d < 4; ++d) {
    const int dk = d * 16 + lcol;
#pragma unroll
    for (int rt = 0; rt < 2; ++rt)
#pragma unroll
      for (int r = 0; r < 4; ++r) {
        const int s = rbase + rt * 16 + kq * 4 + r;
        ctx[(size_t)(b * S_LEN + s) * DMODEL + h * DK + dk] = (f16)o[rt][d][r];
      }
  }
}

extern "C" void kernel_launch(void* const* d_in, const int* in_sizes, int n_in,
                              void* d_out, int out_size, void* d_ws, size_t ws_size,
                              hipStream_t stream) {
  const float* q = (const float*)d_in[0];
  const float* k = (const float*)d_in[1];
  const float* v = (const float*)d_in[2];
  const int* mask = (const int*)d_in[3];
  const float* w_q = (const float*)d_in[4];
  const float* b_q = (const float*)d_in[5];
  const float* w_v = (const float*)d_in[6];
  const float* b_v = (const float*)d_in[7];
  const float* w_o = (const float*)d_in[8];
  const float* b_o = (const float*)d_in[9];

  float* out = (float*)d_out;
  float* attn = out + (size_t)BS * DMODEL;  // output 1 region

  f16* qh = (f16*)d_ws;                  // [B][H][S][DK]
  f16* kh = qh + (size_t)BS * DMODEL;    // [B][H][S][DK]
  f16* vhT = kh + (size_t)BS * DMODEL;   // [B][H][DK][S]
  f16* ctx = vhT + (size_t)BS * DMODEL;  // [BS][DMODEL]
  float* m_arr = (float*)(ctx + (size_t)BS * DMODEL);  // [32*2048]
  float* l_arr = m_arr + (size_t)NH * BATCH * S_LEN;   // [32*2048]

  dim3 gblk(8, 32);
  gemm_nt<float, 0><<<gblk, 256, 0, stream>>>(q, w_q, b_q, qh);
  gemm_nt<float, 0><<<gblk, 256, 0, stream>>>(k, w_q, b_q, kh);
  gemm_nt<float, 1><<<gblk, 256, 0, stream>>>(v, w_v, b_v, vhT);
  stats_kernel<<<dim3(16, 32), 256, 0, stream>>>(qh, kh, mask, m_arr, l_arr);
  attn_pv_kernel<<<dim3(16, 32), 256, 0, stream>>>(qh, kh, vhT, mask, m_arr,
                                                   l_arr, attn, ctx);
  gemm_nt<_Float16, 2><<<gblk, 256, 0, stream>>>(ctx, w_o, b_o, out);
}